// Round 1
// baseline (775.928 us; speedup 1.0000x reference)
//
#include <hip/hip_runtime.h>

// EquivariantLayerNorm: N rows of DIM=480 fp32.
//  [0,128)   : standard LayerNorm over 128 with weight+bias
//  [128,320) : 64 segments x 3, per-segment mean/var norm (no affine)
//  [320,480) : 32 segments x 5, per-segment mean/var norm (no affine)
// One 64-lane wave per row; 4 waves (rows) per 256-thread block.

constexpr int N_ROWS = 262144;
constexpr int S = 128;
constexpr int MUL1 = 64, D1 = 3;
constexpr int MUL2 = 32, D2 = 5;
constexpr int DIM = S + MUL1 * D1 + MUL2 * D2; // 480
constexpr float EPS = 1e-5f;

__global__ __launch_bounds__(256) void eqln_kernel(
    const float* __restrict__ x,
    const float* __restrict__ weight,
    const float* __restrict__ bias,
    float* __restrict__ out)
{
    const int wave = threadIdx.x >> 6;   // 0..3 (row within block)
    const int lane = threadIdx.x & 63;
    const long long row = (long long)blockIdx.x * 4 + wave;

    const float* xr = x + row * DIM;
    float* orow = out + row * DIM;

    // ---- scalar LayerNorm over first 128 elements ----
    // lane i handles elements [2i, 2i+1]; float2 load => 512B per wave instr.
    float2 v = *(const float2*)(xr + 2 * lane);
    float s  = v.x + v.y;
    float sq = v.x * v.x + v.y * v.y;
#pragma unroll
    for (int off = 32; off >= 1; off >>= 1) {
        s  += __shfl_xor(s,  off, 64);
        sq += __shfl_xor(sq, off, 64);
    }
    const float m   = s * (1.0f / 128.0f);
    const float var = sq * (1.0f / 128.0f) - m * m;
    const float r   = rsqrtf(var + EPS);

    float2 w = *(const float2*)(weight + 2 * lane);
    float2 b = *(const float2*)(bias   + 2 * lane);
    float2 o;
    o.x = (v.x - m) * r * w.x + b.x;
    o.y = (v.y - m) * r * w.y + b.y;
    *(float2*)(orow + 2 * lane) = o;

    // ---- v1: 64 segments of 3 (lane i = segment i) ----
    {
        const float* p = xr + S + 3 * lane;
        float a0 = p[0], a1 = p[1], a2 = p[2];
        float mm = (a0 + a1 + a2) * (1.0f / 3.0f);
        float d0 = a0 - mm, d1 = a1 - mm, d2 = a2 - mm;
        float vv = (d0 * d0 + d1 * d1 + d2 * d2) * (1.0f / 3.0f);
        float rr = rsqrtf(vv + EPS);
        float* q = orow + S + 3 * lane;
        q[0] = d0 * rr;
        q[1] = d1 * rr;
        q[2] = d2 * rr;
    }

    // ---- v2: 32 segments of 5 (lanes 0..31) ----
    if (lane < 32) {
        const float* p = xr + S + MUL1 * D1 + 5 * lane;
        float a[5];
#pragma unroll
        for (int i = 0; i < 5; ++i) a[i] = p[i];
        float ssum = 0.0f;
#pragma unroll
        for (int i = 0; i < 5; ++i) ssum += a[i];
        float mm = ssum * 0.2f;
        float vv = 0.0f;
#pragma unroll
        for (int i = 0; i < 5; ++i) { float d = a[i] - mm; vv += d * d; }
        vv *= 0.2f;
        float rr = rsqrtf(vv + EPS);
        float* q = orow + S + MUL1 * D1 + 5 * lane;
#pragma unroll
        for (int i = 0; i < 5; ++i) q[i] = (a[i] - mm) * rr;
    }
}

extern "C" void kernel_launch(void* const* d_in, const int* in_sizes, int n_in,
                              void* d_out, int out_size, void* d_ws, size_t ws_size,
                              hipStream_t stream) {
    const float* x      = (const float*)d_in[0];
    const float* weight = (const float*)d_in[1];
    const float* bias   = (const float*)d_in[2];
    float* out = (float*)d_out;

    const int rows_per_block = 4;
    dim3 grid(N_ROWS / rows_per_block);  // 65536
    dim3 block(256);
    eqln_kernel<<<grid, block, 0, stream>>>(x, weight, bias, out);
}